// Round 1
// baseline (2845.078 us; speedup 1.0000x reference)
//
#include <hip/hip_runtime.h>

// PressureProjection on MI355X — round 7.
// R6 finding: bucket_place at 565us moves 1.34GB (848MB fetch / 461MB write)
// vs ~410MB ideal -> still partial-line-write bound. Footprint model:
// 256 co-resident chunk-blocks x 977 buckets x 2 payload arrays x ~128B open
// granule ~= 8MB/XCD >> 4MB L2 (which also holds the 6MB u_hat gather set).
// R7: shrink active write footprint ~8x so open lines survive until filled:
//  * NBLK 256 -> 64 concurrent chunk-blocks (runs 32 -> 128 edges: A1 runs
//    1KB, A2 runs 1KB -> boundary-only partial granules)
//  * bucket = dst>>10 (1024 nodes/bucket, NB=489); bucket kernels use
//    1024 threads (1 thread per node in bucket)
//  -> footprint 8 blk/XCD x 489 x 2 x 128B ~= 1MB/XCD, fits L2 with margin.
// Predicted: bucket_place WRITE 461->~135MB, FETCH 848->~300MB, 565->~150us.
// No memset: every workspace array fully written before read.

#define TPB 256
#define TPB_A 1024
#define KB 2048          // grid for CG vector kernels & partial arrays
#define NBLK 64          // chunks for bucket sort (R7: 256 -> 64)
#define BSHIFT 10        // bucket = dst >> 10 (1024 nodes per bucket)
#define BSIZE 1024       // nodes per bucket == threads per bucket kernel
#define TPB_B BSIZE
#define MAXNB 512        // max coarse buckets (N <= 524288)
#define CG_ITERS 20
#define TOL2 1e-8f       // (CG_TOL=1e-4)^2

struct Sum3 { float a, b, c; };

// block-wide sums of three arrays of length n, broadcast (TPB threads)
__device__ inline Sum3 block_sum3_bcast(const float* __restrict__ A,
                                        const float* __restrict__ B,
                                        const float* __restrict__ C, int n) {
  float va = 0.f, vb = 0.f, vc = 0.f;
  for (int k = threadIdx.x; k < n; k += TPB) { va += A[k]; vb += B[k]; vc += C[k]; }
#pragma unroll
  for (int o = 32; o; o >>= 1) {
    va += __shfl_down(va, o, 64);
    vb += __shfl_down(vb, o, 64);
    vc += __shfl_down(vc, o, 64);
  }
  __shared__ float sa[TPB / 64], sb[TPB / 64], sc[TPB / 64], bc[3];
  int lane = threadIdx.x & 63, wid = threadIdx.x >> 6;
  if (lane == 0) { sa[wid] = va; sb[wid] = vb; sc[wid] = vc; }
  __syncthreads();
  if (threadIdx.x == 0) {
    float ta = 0.f, tb = 0.f, tc = 0.f;
#pragma unroll
    for (int k = 0; k < TPB / 64; k++) { ta += sa[k]; tb += sb[k]; tc += sc[k]; }
    bc[0] = ta; bc[1] = tb; bc[2] = tc;
  }
  __syncthreads();
  Sum3 r{bc[0], bc[1], bc[2]};
  __syncthreads();
  return r;
}

template <int BS>
__device__ inline void block_reduce1_store(float v1, float* d1) {
#pragma unroll
  for (int o = 32; o; o >>= 1) v1 += __shfl_down(v1, o, 64);
  __shared__ float s1[BS / 64];
  int lane = threadIdx.x & 63, wid = threadIdx.x >> 6;
  if (lane == 0) s1[wid] = v1;
  __syncthreads();
  if (threadIdx.x == 0) {
    float t1 = 0.f;
#pragma unroll
    for (int k = 0; k < BS / 64; k++) t1 += s1[k];
    *d1 = t1;
  }
}

template <int BS>
__device__ inline void block_reduce2_store(float v1, float v2, float* d1, float* d2) {
#pragma unroll
  for (int o = 32; o; o >>= 1) {
    v1 += __shfl_down(v1, o, 64);
    v2 += __shfl_down(v2, o, 64);
  }
  __shared__ float s1[BS / 64], s2[BS / 64];
  int lane = threadIdx.x & 63, wid = threadIdx.x >> 6;
  if (lane == 0) { s1[wid] = v1; s2[wid] = v2; }
  __syncthreads();
  if (threadIdx.x == 0) {
    float t1 = 0.f, t2 = 0.f;
#pragma unroll
    for (int k = 0; k < BS / 64; k++) { t1 += s1[k]; t2 += s2[k]; }
    *d1 = t1;
    *d2 = t2;
  }
}

// ---- pass A0: per-chunk LDS histogram of coarse buckets ----
__global__ __launch_bounds__(TPB_A) void bucket_hist(
    const int* __restrict__ ei, unsigned* __restrict__ mat,
    int E, int NB, int chunk) {
  __shared__ unsigned cntL[MAXNB];
  for (int i = threadIdx.x; i < NB; i += TPB_A) cntL[i] = 0;
  __syncthreads();
  int blk = blockIdx.x;
  int e0 = blk * chunk, e1 = min(E, e0 + chunk);
  for (int e = e0 + threadIdx.x; e < e1; e += TPB_A)
    atomicAdd(&cntL[((unsigned)ei[E + e]) >> BSHIFT], 1u);
  __syncthreads();
  for (int b = threadIdx.x; b < NB; b += TPB_A)
    mat[(size_t)b * NBLK + blk] = cntL[b];
}

// ---- scan (1024 elems / block) ----
__global__ __launch_bounds__(TPB) void scan_blocks(
    const unsigned* __restrict__ cnt, unsigned* __restrict__ offs,
    unsigned* __restrict__ btot, int n) {
  __shared__ unsigned sd[TPB];
  int t = threadIdx.x;
  int base = blockIdx.x * 1024 + t * 4;
  unsigned v0 = 0, v1 = 0, v2 = 0, v3 = 0;
  if (base + 0 < n) v0 = cnt[base + 0];
  if (base + 1 < n) v1 = cnt[base + 1];
  if (base + 2 < n) v2 = cnt[base + 2];
  if (base + 3 < n) v3 = cnt[base + 3];
  unsigned local = v0 + v1 + v2 + v3;
  sd[t] = local;
  __syncthreads();
  for (int o = 1; o < TPB; o <<= 1) {
    unsigned x = (t >= o) ? sd[t - o] : 0u;
    __syncthreads();
    sd[t] += x;
    __syncthreads();
  }
  unsigned excl = sd[t] - local;
  if (base + 0 < n) offs[base + 0] = excl; excl += v0;
  if (base + 1 < n) offs[base + 1] = excl; excl += v1;
  if (base + 2 < n) offs[base + 2] = excl; excl += v2;
  if (base + 3 < n) offs[base + 3] = excl;
  if (t == TPB - 1) btot[blockIdx.x] = sd[TPB - 1];
}

__global__ __launch_bounds__(512) void scan_totals(unsigned* __restrict__ btot, int nb) {
  __shared__ unsigned sd[512];
  int t = threadIdx.x;
  unsigned v = (t < nb) ? btot[t] : 0u;
  sd[t] = v;
  __syncthreads();
  for (int o = 1; o < 512; o <<= 1) {
    unsigned x = (t >= o) ? sd[t - o] : 0u;
    __syncthreads();
    sd[t] += x;
    __syncthreads();
  }
  if (t < nb) btot[t] = sd[t] - v;  // exclusive
}

__global__ __launch_bounds__(TPB) void scan_add(
    unsigned* __restrict__ offs, const unsigned* __restrict__ btot,
    int n, unsigned total) {
  int i = blockIdx.x * TPB + threadIdx.x;
  if (i < n) offs[i] += btot[i >> 10];
  if (i == 0) offs[n] = total;
}

// ---- pass A1: compute w/flux, place edges into bucket regions ----
__global__ __launch_bounds__(TPB_A) void bucket_place(
    const int* __restrict__ ei, const float* __restrict__ u_hat,
    const float* __restrict__ fn, const float* __restrict__ fa,
    const float* __restrict__ fd, const unsigned* __restrict__ offs,
    unsigned long long* __restrict__ A1, int2* __restrict__ A2,
    int E, int NB, int chunk) {
  __shared__ unsigned cntL[MAXNB];
  __shared__ unsigned offL[MAXNB];
  int blk = blockIdx.x;
  for (int i = threadIdx.x; i < NB; i += TPB_A) {
    cntL[i] = 0;
    offL[i] = offs[(size_t)i * NBLK + blk];
  }
  __syncthreads();
  int e0 = blk * chunk, e1 = min(E, e0 + chunk);
  for (int e = e0 + threadIdx.x; e < e1; e += TPB_A) {
    int s = ei[e], d = ei[E + e];
    float area = fa[e];
    float w = area / fmaxf(fd[e], 1e-8f);
    float ux = 0.5f * (u_hat[3 * s]     + u_hat[3 * d]);
    float uy = 0.5f * (u_hat[3 * s + 1] + u_hat[3 * d + 1]);
    float uz = 0.5f * (u_hat[3 * s + 2] + u_hat[3 * d + 2]);
    float flux = (ux * fn[3 * e] + uy * fn[3 * e + 1] + uz * fn[3 * e + 2]) * area;
    unsigned b = ((unsigned)d) >> BSHIFT;
    unsigned dl = ((unsigned)d) & (BSIZE - 1u);
    unsigned r = atomicAdd(&cntL[b], 1u);
    unsigned pos = offL[b] + r;
    unsigned hi = (dl << 19) | (unsigned)s;
    A1[pos] = ((unsigned long long)hi << 32) | (unsigned long long)__float_as_uint(w);
    A2[pos] = make_int2(e, __float_as_int(flux));
  }
}

// ---- CG setup: per-bucket LDS sums of w and flux ----
__global__ __launch_bounds__(TPB_B) void node_setup(
    const unsigned long long* __restrict__ A1, const int2* __restrict__ A2,
    const unsigned* __restrict__ offs, const float* __restrict__ cv,
    float* __restrict__ diag, float* __restrict__ r, float* __restrict__ p,
    float* __restrict__ phi, float* __restrict__ minv,
    float* __restrict__ rz_part, float* __restrict__ rr_part, int N, int NB) {
  __shared__ float wacc[TPB_B], facc[TPB_B];
  int b = blockIdx.x;
  float rzv = 0.f, rrv = 0.f;
  if (b < NB) {
    wacc[threadIdx.x] = 0.f;
    facc[threadIdx.x] = 0.f;
    __syncthreads();
    unsigned jb = offs[(size_t)b * NBLK], je = offs[(size_t)(b + 1) * NBLK];
    for (unsigned j = jb + threadIdx.x; j < je; j += TPB_B) {
      unsigned long long v = A1[j];
      unsigned hi = (unsigned)(v >> 32);
      float w = __uint_as_float((unsigned)v);
      atomicAdd(&wacc[hi >> 19], w);
      atomicAdd(&facc[hi >> 19], __int_as_float(A2[j].y));
    }
    __syncthreads();
    int node = (b << BSHIFT) + threadIdx.x;
    if (node < N) {
      float wsum = wacc[threadIdx.x];
      float vol = fmaxf(cv[node], 1e-12f);
      float bval = facc[threadIdx.x] / vol;
      float mi = 1.0f / fmaxf(wsum, 1e-8f);
      diag[node] = wsum;
      minv[node] = mi;
      r[node] = bval;
      phi[node] = 0.f;
      float pi = mi * bval;
      p[node] = pi;
      rzv = bval * pi;
      rrv = bval * bval;
    }
  }
  block_reduce2_store<TPB_B>(rzv, rrv, &rz_part[blockIdx.x], &rr_part[blockIdx.x]);
}

// ---- matvec: per-bucket LDS accumulate of w*p[src] ----
__global__ __launch_bounds__(TPB_B) void matvec(
    const float* __restrict__ p, const float* __restrict__ diag,
    const unsigned* __restrict__ offs, const unsigned long long* __restrict__ A1,
    float* __restrict__ ap, float* __restrict__ pap_part, int N, int NB) {
  __shared__ float acc[TPB_B];
  int b = blockIdx.x;
  float contrib = 0.f;
  if (b < NB) {
    acc[threadIdx.x] = 0.f;
    __syncthreads();
    unsigned jb = offs[(size_t)b * NBLK], je = offs[(size_t)(b + 1) * NBLK];
    for (unsigned j = jb + threadIdx.x; j < je; j += TPB_B) {
      unsigned long long v = A1[j];
      unsigned hi = (unsigned)(v >> 32);
      float w = __uint_as_float((unsigned)v);
      atomicAdd(&acc[hi >> 19], w * p[hi & 0x7FFFFu]);
    }
    __syncthreads();
    int node = (b << BSHIFT) + threadIdx.x;
    if (node < N) {
      float pi = p[node];
      float api = diag[node] * pi - acc[threadIdx.x];
      ap[node] = api;
      contrib = pi * api;
    }
  }
  block_reduce1_store<TPB_B>(contrib, &pap_part[blockIdx.x]);
}

// ---- gated phi/r update; emits rz/rr partials for next iter ----
__global__ __launch_bounds__(TPB) void cg_update(
    float* __restrict__ phi, float* __restrict__ r, const float* __restrict__ p,
    const float* __restrict__ ap, const float* __restrict__ minv,
    const float* __restrict__ pap_it, const float* __restrict__ rz_it,
    const float* __restrict__ rr_it, float* __restrict__ rz_next,
    float* __restrict__ rr_next, int N) {
  Sum3 s = block_sum3_bcast(pap_it, rz_it, rr_it, KB);
  bool act = (s.c >= TOL2);
  float alpha = s.b / (s.a + 1e-12f);
  float rzacc = 0.f, rracc = 0.f;
  for (int i = blockIdx.x * TPB + threadIdx.x; i < N; i += KB * TPB) {
    float ri = r[i];
    if (act) {
      phi[i] += alpha * p[i];
      ri -= alpha * ap[i];
      r[i] = ri;
    }
    float zi = minv[i] * ri;
    rzacc += ri * zi;
    rracc += ri * ri;
  }
  block_reduce2_store<TPB>(rzacc, rracc, &rz_next[blockIdx.x], &rr_next[blockIdx.x]);
}

// ---- gated p = z + beta*p ----
__global__ __launch_bounds__(TPB) void p_update(
    float* __restrict__ p, const float* __restrict__ r,
    const float* __restrict__ minv, const float* __restrict__ rz_next,
    const float* __restrict__ rz_it, const float* __restrict__ rr_it, int N) {
  Sum3 s = block_sum3_bcast(rz_next, rz_it, rr_it, KB);
  if (s.c < TOL2) return;  // frozen: p unchanged
  float beta = s.a / (s.b + 1e-12f);
  for (int i = blockIdx.x * TPB + threadIdx.x; i < N; i += KB * TPB) {
    p[i] = minv[i] * r[i] + beta * p[i];
  }
}

// ---- pressure correction + output: per-bucket LDS grad accumulate ----
__global__ __launch_bounds__(TPB_B) void finalize(
    const float* __restrict__ u_hat, const float* __restrict__ cv,
    const float* __restrict__ phi, const unsigned* __restrict__ offs,
    const unsigned long long* __restrict__ A1, const int2* __restrict__ A2,
    const float* __restrict__ fn, float* __restrict__ out, int N, int NB) {
  __shared__ float gxa[TPB_B], gya[TPB_B], gza[TPB_B];
  int b = blockIdx.x;
  if (b >= NB) return;
  gxa[threadIdx.x] = 0.f;
  gya[threadIdx.x] = 0.f;
  gza[threadIdx.x] = 0.f;
  __syncthreads();
  unsigned jb = offs[(size_t)b * NBLK], je = offs[(size_t)(b + 1) * NBLK];
  for (unsigned j = jb + threadIdx.x; j < je; j += TPB_B) {
    unsigned long long v = A1[j];
    unsigned hi = (unsigned)(v >> 32);
    float w = __uint_as_float((unsigned)v);
    float t = w * phi[hi & 0x7FFFFu];
    int e = A2[j].x;
    int dl = hi >> 19;
    atomicAdd(&gxa[dl], t * fn[3 * e]);
    atomicAdd(&gya[dl], t * fn[3 * e + 1]);
    atomicAdd(&gza[dl], t * fn[3 * e + 2]);
  }
  __syncthreads();
  int node = (b << BSHIFT) + threadIdx.x;
  if (node < N) {
    float iv = 1.0f / fmaxf(cv[node], 1e-12f);
    out[3 * node]     = u_hat[3 * node]     - gxa[threadIdx.x] * iv;
    out[3 * node + 1] = u_hat[3 * node + 1] - gya[threadIdx.x] * iv;
    out[3 * node + 2] = u_hat[3 * node + 2] - gza[threadIdx.x] * iv;
    out[3 * N + node] = phi[node];
  }
}

extern "C" void kernel_launch(void* const* d_in, const int* in_sizes, int n_in,
                              void* d_out, int out_size, void* d_ws, size_t ws_size,
                              hipStream_t stream) {
  const float* u_hat = (const float*)d_in[0];
  const int*   ei    = (const int*)d_in[1];
  const float* fn    = (const float*)d_in[2];
  const float* fa    = (const float*)d_in[3];
  const float* fd    = (const float*)d_in[4];
  const float* cv    = (const float*)d_in[5];
  float* out = (float*)d_out;

  const int N = in_sizes[0] / 3;   // 500,000
  const int E = in_sizes[1] / 2;   // 8,000,000
  const int NB = (N + BSIZE - 1) >> BSHIFT;  // coarse buckets (489)
  const int NS = NB * NBLK;        // scan length (31,296)
  const int chunk = (E + NBLK - 1) / NBLK;

  // ---- workspace bump allocator (256B aligned); ~145 MB ----
  char* base = (char*)d_ws;
  size_t off = 0;
  auto alloc = [&](size_t bytes) -> void* {
    void* ptr = base + off;
    off = (off + bytes + 255) & ~size_t(255);
    return ptr;
  };
  unsigned* mat   = (unsigned*)alloc((size_t)NS * 4);
  unsigned* offs  = (unsigned*)alloc((size_t)(NS + 1) * 4);
  unsigned* btot  = (unsigned*)alloc(512 * 4);
  float*    diag  = (float*)alloc((size_t)N * 4);
  float*    minv  = (float*)alloc((size_t)N * 4);
  float*    phi   = (float*)alloc((size_t)N * 4);
  float*    rvec  = (float*)alloc((size_t)N * 4);
  float*    pvec  = (float*)alloc((size_t)N * 4);
  float*    ap    = (float*)alloc((size_t)N * 4);
  float*    rzrr  = (float*)alloc((size_t)(2 * (CG_ITERS + 1)) * KB * 4);
  float*    papp  = (float*)alloc((size_t)CG_ITERS * KB * 4);
  unsigned long long* A1 = (unsigned long long*)alloc((size_t)E * 8);
  int2*     A2    = (int2*)alloc((size_t)E * 8);
  (void)ws_size; (void)n_in; (void)out_size;

  auto rz_part = [&](int it) { return rzrr + (size_t)(2 * it) * KB; };
  auto rr_part = [&](int it) { return rzrr + (size_t)(2 * it + 1) * KB; };
  auto pap_part = [&](int it) { return papp + (size_t)it * KB; };

  const int nbScan = (NS + 1023) / 1024;          // 31 <= 512
  const int gridScanAdd = (NS + TPB - 1) / TPB;

  bucket_hist<<<NBLK, TPB_A, 0, stream>>>(ei, mat, E, NB, chunk);

  scan_blocks<<<nbScan, TPB, 0, stream>>>(mat, offs, btot, NS);
  scan_totals<<<1, 512, 0, stream>>>(btot, nbScan);
  scan_add<<<gridScanAdd, TPB, 0, stream>>>(offs, btot, NS, (unsigned)E);

  bucket_place<<<NBLK, TPB_A, 0, stream>>>(ei, u_hat, fn, fa, fd, offs,
                                           A1, A2, E, NB, chunk);

  node_setup<<<KB, TPB_B, 0, stream>>>(A1, A2, offs, cv, diag,
                                       rvec, pvec, phi, minv,
                                       rz_part(0), rr_part(0), N, NB);

  for (int it = 0; it < CG_ITERS; it++) {
    matvec<<<KB, TPB_B, 0, stream>>>(pvec, diag, offs, A1, ap,
                                     pap_part(it), N, NB);
    cg_update<<<KB, TPB, 0, stream>>>(phi, rvec, pvec, ap, minv,
                                      pap_part(it), rz_part(it), rr_part(it),
                                      rz_part(it + 1), rr_part(it + 1), N);
    if (it < CG_ITERS - 1) {
      p_update<<<KB, TPB, 0, stream>>>(pvec, rvec, minv,
                                       rz_part(it + 1), rz_part(it),
                                       rr_part(it), N);
    }
  }

  finalize<<<NB, TPB_B, 0, stream>>>(u_hat, cv, phi, offs, A1, A2,
                                     fn, out, N, NB);
}

// Round 2
// 2790.802 us; speedup vs baseline: 1.0194x; 1.0194x over previous
//
#include <hip/hip_runtime.h>

// PressureProjection on MI355X — round 8.
// R7 post-mortem (NBLK 256->64): traffic only -15% (1.34->1.14GB) but
// occupancy 37->9.3% -> latency-bound, 565->1042us. Conclusion: the excess
// traffic is STRUCTURAL (RFO on scattered 8-B payload stores + u_hat gather
// thrash), not capacity-eviction; concurrency is the binding constraint.
// R8 (at full NBLK=256 concurrency):
//  * ONE 16-B payload entry {hi,w,flux,eid} per edge, single dwordx4 store
//    (halves scattered-store transactions and open-line streams vs two 8-B
//    arrays); BSHIFT=10 -> 489 buckets -> ~2MB open lines/XCD.
//  * node_setup (which streams the payload once anyway) splits out the dense
//    8-B hot stream A1hot={hi,w} for matvec (sequential full-line writes).
//  * p_update fused into matvec: beta reduced from partials at kernel start,
//    p computed on the fly from z + beta*p_old (ping-pong buffers); removes
//    19 launches + 19 full N-sweeps.
// Predicted: bucket_place 565->~250us (WRITE 460->~140MB, FETCH 848->~400MB),
// total 2307->~1850us. Fallback: if ws_size < ~210MB, A1hot is skipped and
// matvec strides the 16-B array (correct, slower).

#define TPB 256
#define TPB_A 1024
#define KB 2048          // grid for CG vector kernels & partial arrays
#define NBLK 256         // chunks for bucket sort (R8: back to 256)
#define BSHIFT 10        // bucket = dst >> 10 (1024 nodes per bucket)
#define BSIZE 1024       // nodes per bucket == threads per bucket kernel
#define TPB_B BSIZE
#define MAXNB 512        // max coarse buckets (N <= 524288)
#define CG_ITERS 20
#define TOL2 1e-8f       // (CG_TOL=1e-4)^2

struct Sum3 { float a, b, c; };

// block-wide sums of three arrays of length n, broadcast (BS threads)
template <int BS>
__device__ inline Sum3 block_sum3_bcast(const float* __restrict__ A,
                                        const float* __restrict__ B,
                                        const float* __restrict__ C, int n) {
  float va = 0.f, vb = 0.f, vc = 0.f;
  for (int k = threadIdx.x; k < n; k += BS) { va += A[k]; vb += B[k]; vc += C[k]; }
#pragma unroll
  for (int o = 32; o; o >>= 1) {
    va += __shfl_down(va, o, 64);
    vb += __shfl_down(vb, o, 64);
    vc += __shfl_down(vc, o, 64);
  }
  __shared__ float sa[BS / 64], sb[BS / 64], sc[BS / 64], bc[3];
  int lane = threadIdx.x & 63, wid = threadIdx.x >> 6;
  if (lane == 0) { sa[wid] = va; sb[wid] = vb; sc[wid] = vc; }
  __syncthreads();
  if (threadIdx.x == 0) {
    float ta = 0.f, tb = 0.f, tc = 0.f;
#pragma unroll
    for (int k = 0; k < BS / 64; k++) { ta += sa[k]; tb += sb[k]; tc += sc[k]; }
    bc[0] = ta; bc[1] = tb; bc[2] = tc;
  }
  __syncthreads();
  Sum3 r{bc[0], bc[1], bc[2]};
  __syncthreads();
  return r;
}

template <int BS>
__device__ inline void block_reduce1_store(float v1, float* d1) {
#pragma unroll
  for (int o = 32; o; o >>= 1) v1 += __shfl_down(v1, o, 64);
  __shared__ float s1[BS / 64];
  int lane = threadIdx.x & 63, wid = threadIdx.x >> 6;
  if (lane == 0) s1[wid] = v1;
  __syncthreads();
  if (threadIdx.x == 0) {
    float t1 = 0.f;
#pragma unroll
    for (int k = 0; k < BS / 64; k++) t1 += s1[k];
    *d1 = t1;
  }
}

template <int BS>
__device__ inline void block_reduce2_store(float v1, float v2, float* d1, float* d2) {
#pragma unroll
  for (int o = 32; o; o >>= 1) {
    v1 += __shfl_down(v1, o, 64);
    v2 += __shfl_down(v2, o, 64);
  }
  __shared__ float s1[BS / 64], s2[BS / 64];
  int lane = threadIdx.x & 63, wid = threadIdx.x >> 6;
  if (lane == 0) { s1[wid] = v1; s2[wid] = v2; }
  __syncthreads();
  if (threadIdx.x == 0) {
    float t1 = 0.f, t2 = 0.f;
#pragma unroll
    for (int k = 0; k < BS / 64; k++) { t1 += s1[k]; t2 += s2[k]; }
    *d1 = t1;
    *d2 = t2;
  }
}

// ---- pass A0: per-chunk LDS histogram of coarse buckets ----
__global__ __launch_bounds__(TPB_A) void bucket_hist(
    const int* __restrict__ ei, unsigned* __restrict__ mat,
    int E, int NB, int chunk) {
  __shared__ unsigned cntL[MAXNB];
  for (int i = threadIdx.x; i < NB; i += TPB_A) cntL[i] = 0;
  __syncthreads();
  int blk = blockIdx.x;
  int e0 = blk * chunk, e1 = min(E, e0 + chunk);
  for (int e = e0 + threadIdx.x; e < e1; e += TPB_A)
    atomicAdd(&cntL[((unsigned)ei[E + e]) >> BSHIFT], 1u);
  __syncthreads();
  for (int b = threadIdx.x; b < NB; b += TPB_A)
    mat[(size_t)b * NBLK + blk] = cntL[b];
}

// ---- scan (1024 elems / block) ----
__global__ __launch_bounds__(TPB) void scan_blocks(
    const unsigned* __restrict__ cnt, unsigned* __restrict__ offs,
    unsigned* __restrict__ btot, int n) {
  __shared__ unsigned sd[TPB];
  int t = threadIdx.x;
  int base = blockIdx.x * 1024 + t * 4;
  unsigned v0 = 0, v1 = 0, v2 = 0, v3 = 0;
  if (base + 0 < n) v0 = cnt[base + 0];
  if (base + 1 < n) v1 = cnt[base + 1];
  if (base + 2 < n) v2 = cnt[base + 2];
  if (base + 3 < n) v3 = cnt[base + 3];
  unsigned local = v0 + v1 + v2 + v3;
  sd[t] = local;
  __syncthreads();
  for (int o = 1; o < TPB; o <<= 1) {
    unsigned x = (t >= o) ? sd[t - o] : 0u;
    __syncthreads();
    sd[t] += x;
    __syncthreads();
  }
  unsigned excl = sd[t] - local;
  if (base + 0 < n) offs[base + 0] = excl; excl += v0;
  if (base + 1 < n) offs[base + 1] = excl; excl += v1;
  if (base + 2 < n) offs[base + 2] = excl; excl += v2;
  if (base + 3 < n) offs[base + 3] = excl;
  if (t == TPB - 1) btot[blockIdx.x] = sd[TPB - 1];
}

__global__ __launch_bounds__(512) void scan_totals(unsigned* __restrict__ btot, int nb) {
  __shared__ unsigned sd[512];
  int t = threadIdx.x;
  unsigned v = (t < nb) ? btot[t] : 0u;
  sd[t] = v;
  __syncthreads();
  for (int o = 1; o < 512; o <<= 1) {
    unsigned x = (t >= o) ? sd[t - o] : 0u;
    __syncthreads();
    sd[t] += x;
    __syncthreads();
  }
  if (t < nb) btot[t] = sd[t] - v;  // exclusive
}

__global__ __launch_bounds__(TPB) void scan_add(
    unsigned* __restrict__ offs, const unsigned* __restrict__ btot,
    int n, unsigned total) {
  int i = blockIdx.x * TPB + threadIdx.x;
  if (i < n) offs[i] += btot[i >> 10];
  if (i == 0) offs[n] = total;
}

// ---- pass A1: compute w/flux, place edges as ONE 16-B entry ----
__global__ __launch_bounds__(TPB_A) void bucket_place(
    const int* __restrict__ ei, const float* __restrict__ u_hat,
    const float* __restrict__ fn, const float* __restrict__ fa,
    const float* __restrict__ fd, const unsigned* __restrict__ offs,
    uint4* __restrict__ A16, int E, int NB, int chunk) {
  __shared__ unsigned cntL[MAXNB];
  __shared__ unsigned offL[MAXNB];
  int blk = blockIdx.x;
  for (int i = threadIdx.x; i < NB; i += TPB_A) {
    cntL[i] = 0;
    offL[i] = offs[(size_t)i * NBLK + blk];
  }
  __syncthreads();
  int e0 = blk * chunk, e1 = min(E, e0 + chunk);
  for (int e = e0 + threadIdx.x; e < e1; e += TPB_A) {
    int s = ei[e], d = ei[E + e];
    float area = fa[e];
    float w = area / fmaxf(fd[e], 1e-8f);
    float ux = 0.5f * (u_hat[3 * s]     + u_hat[3 * d]);
    float uy = 0.5f * (u_hat[3 * s + 1] + u_hat[3 * d + 1]);
    float uz = 0.5f * (u_hat[3 * s + 2] + u_hat[3 * d + 2]);
    float flux = (ux * fn[3 * e] + uy * fn[3 * e + 1] + uz * fn[3 * e + 2]) * area;
    unsigned b = ((unsigned)d) >> BSHIFT;
    unsigned dl = ((unsigned)d) & (BSIZE - 1u);
    unsigned r = atomicAdd(&cntL[b], 1u);
    unsigned pos = offL[b] + r;
    unsigned hi = (dl << 19) | (unsigned)s;
    A16[(size_t)pos] = make_uint4(hi, __float_as_uint(w),
                                  __float_as_uint(flux), (unsigned)e);
  }
}

// ---- CG setup: per-bucket LDS sums of w and flux; splits hot A1 stream ----
__global__ __launch_bounds__(TPB_B) void node_setup(
    const uint4* __restrict__ A16, unsigned long long* __restrict__ A1hot,
    const unsigned* __restrict__ offs, const float* __restrict__ cv,
    float* __restrict__ diag, float* __restrict__ r, float* __restrict__ p,
    float* __restrict__ phi, float* __restrict__ minv,
    float* __restrict__ rz_part, float* __restrict__ rr_part, int N, int NB) {
  __shared__ float wacc[TPB_B], facc[TPB_B];
  int b = blockIdx.x;
  float rzv = 0.f, rrv = 0.f;
  if (b < NB) {
    wacc[threadIdx.x] = 0.f;
    facc[threadIdx.x] = 0.f;
    __syncthreads();
    unsigned jb = offs[(size_t)b * NBLK], je = offs[(size_t)(b + 1) * NBLK];
    if (A1hot) {
      for (unsigned j = jb + threadIdx.x; j < je; j += TPB_B) {
        uint4 v = A16[(size_t)j];
        atomicAdd(&wacc[v.x >> 19], __uint_as_float(v.y));
        atomicAdd(&facc[v.x >> 19], __uint_as_float(v.z));
        A1hot[(size_t)j] = ((unsigned long long)v.x << 32) | (unsigned long long)v.y;
      }
    } else {
      for (unsigned j = jb + threadIdx.x; j < je; j += TPB_B) {
        uint4 v = A16[(size_t)j];
        atomicAdd(&wacc[v.x >> 19], __uint_as_float(v.y));
        atomicAdd(&facc[v.x >> 19], __uint_as_float(v.z));
      }
    }
    __syncthreads();
    int node = (b << BSHIFT) + threadIdx.x;
    if (node < N) {
      float wsum = wacc[threadIdx.x];
      float vol = fmaxf(cv[node], 1e-12f);
      float bval = facc[threadIdx.x] / vol;
      float mi = 1.0f / fmaxf(wsum, 1e-8f);
      diag[node] = wsum;
      minv[node] = mi;
      r[node] = bval;
      phi[node] = 0.f;
      float pi = mi * bval;
      p[node] = pi;
      rzv = bval * pi;
      rrv = bval * bval;
    }
  }
  block_reduce2_store<TPB_B>(rzv, rrv, &rz_part[blockIdx.x], &rr_part[blockIdx.x]);
}

// ---- matvec with fused p-update: p_new = z + beta*p_old computed on the fly.
// beta from partials at kernel start (iter>=1). Ping-pong p buffers so
// gathers of p_old never race with writes of p_new.
__global__ __launch_bounds__(TPB_B) void matvec(
    const float* __restrict__ p_old, float* __restrict__ p_new,
    const float* __restrict__ z, const float* __restrict__ diag,
    const unsigned* __restrict__ offs,
    const unsigned long long* __restrict__ A1hot, const uint4* __restrict__ A16,
    float* __restrict__ ap, float* __restrict__ pap_part,
    const float* __restrict__ rzJ_part, const float* __restrict__ rzJm1_part,
    const float* __restrict__ rrJm1_part, int N, int NB, int first) {
  float beta = 0.f;
  bool actp = false;
  if (!first) {
    Sum3 s = block_sum3_bcast<TPB_B>(rzJ_part, rzJm1_part, rrJm1_part, KB);
    actp = (s.c >= TOL2);
    beta = s.a / (s.b + 1e-12f);
  }
  bool fuse = (!first) && actp;
  __shared__ float acc[TPB_B];
  int b = blockIdx.x;
  float contrib = 0.f;
  if (b < NB) {
    acc[threadIdx.x] = 0.f;
    __syncthreads();
    unsigned jb = offs[(size_t)b * NBLK], je = offs[(size_t)(b + 1) * NBLK];
    if (A1hot) {
      for (unsigned j = jb + threadIdx.x; j < je; j += TPB_B) {
        unsigned long long v = A1hot[(size_t)j];
        unsigned hi = (unsigned)(v >> 32);
        float w = __uint_as_float((unsigned)v);
        unsigned srcn = hi & 0x7FFFFu;
        float pe = fuse ? fmaf(beta, p_old[srcn], z[srcn]) : p_old[srcn];
        atomicAdd(&acc[hi >> 19], w * pe);
      }
    } else {
      const uint2* A8 = (const uint2*)A16;
      for (unsigned j = jb + threadIdx.x; j < je; j += TPB_B) {
        uint2 v = A8[(size_t)2 * j];
        unsigned hi = v.x;
        float w = __uint_as_float(v.y);
        unsigned srcn = hi & 0x7FFFFu;
        float pe = fuse ? fmaf(beta, p_old[srcn], z[srcn]) : p_old[srcn];
        atomicAdd(&acc[hi >> 19], w * pe);
      }
    }
    __syncthreads();
    int node = (b << BSHIFT) + threadIdx.x;
    if (node < N) {
      float pold = p_old[node];
      float pi = fuse ? fmaf(beta, pold, z[node]) : pold;
      if (!first) p_new[node] = pi;  // copy-forward when frozen
      float api = diag[node] * pi - acc[threadIdx.x];
      ap[node] = api;
      contrib = pi * api;
    }
  }
  block_reduce1_store<TPB_B>(contrib, &pap_part[blockIdx.x]);
}

// ---- gated phi/r update; writes z = minv*r; emits rz/rr partials ----
__global__ __launch_bounds__(TPB) void cg_update(
    float* __restrict__ phi, float* __restrict__ r, const float* __restrict__ p,
    const float* __restrict__ ap, const float* __restrict__ minv,
    float* __restrict__ z,
    const float* __restrict__ pap_it, const float* __restrict__ rz_it,
    const float* __restrict__ rr_it, float* __restrict__ rz_next,
    float* __restrict__ rr_next, int N) {
  Sum3 s = block_sum3_bcast<TPB>(pap_it, rz_it, rr_it, KB);
  bool act = (s.c >= TOL2);
  float alpha = s.b / (s.a + 1e-12f);
  float rzacc = 0.f, rracc = 0.f;
  for (int i = blockIdx.x * TPB + threadIdx.x; i < N; i += KB * TPB) {
    float ri = r[i];
    if (act) {
      phi[i] += alpha * p[i];
      ri -= alpha * ap[i];
      r[i] = ri;
    }
    float zi = minv[i] * ri;
    z[i] = zi;
    rzacc += ri * zi;
    rracc += ri * ri;
  }
  block_reduce2_store<TPB>(rzacc, rracc, &rz_next[blockIdx.x], &rr_next[blockIdx.x]);
}

// ---- pressure correction + output: per-bucket LDS grad accumulate ----
__global__ __launch_bounds__(TPB_B) void finalize(
    const float* __restrict__ u_hat, const float* __restrict__ cv,
    const float* __restrict__ phi, const unsigned* __restrict__ offs,
    const uint4* __restrict__ A16, const float* __restrict__ fn,
    float* __restrict__ out, int N, int NB) {
  __shared__ float gxa[TPB_B], gya[TPB_B], gza[TPB_B];
  int b = blockIdx.x;
  if (b >= NB) return;
  gxa[threadIdx.x] = 0.f;
  gya[threadIdx.x] = 0.f;
  gza[threadIdx.x] = 0.f;
  __syncthreads();
  unsigned jb = offs[(size_t)b * NBLK], je = offs[(size_t)(b + 1) * NBLK];
  for (unsigned j = jb + threadIdx.x; j < je; j += TPB_B) {
    uint4 v = A16[(size_t)j];
    unsigned hi = v.x;
    float w = __uint_as_float(v.y);
    float t = w * phi[hi & 0x7FFFFu];
    int e = (int)v.w;
    int dl = hi >> 19;
    atomicAdd(&gxa[dl], t * fn[3 * e]);
    atomicAdd(&gya[dl], t * fn[3 * e + 1]);
    atomicAdd(&gza[dl], t * fn[3 * e + 2]);
  }
  __syncthreads();
  int node = (b << BSHIFT) + threadIdx.x;
  if (node < N) {
    float iv = 1.0f / fmaxf(cv[node], 1e-12f);
    out[3 * node]     = u_hat[3 * node]     - gxa[threadIdx.x] * iv;
    out[3 * node + 1] = u_hat[3 * node + 1] - gya[threadIdx.x] * iv;
    out[3 * node + 2] = u_hat[3 * node + 2] - gza[threadIdx.x] * iv;
    out[3 * N + node] = phi[node];
  }
}

extern "C" void kernel_launch(void* const* d_in, const int* in_sizes, int n_in,
                              void* d_out, int out_size, void* d_ws, size_t ws_size,
                              hipStream_t stream) {
  const float* u_hat = (const float*)d_in[0];
  const int*   ei    = (const int*)d_in[1];
  const float* fn    = (const float*)d_in[2];
  const float* fa    = (const float*)d_in[3];
  const float* fd    = (const float*)d_in[4];
  const float* cv    = (const float*)d_in[5];
  float* out = (float*)d_out;

  const int N = in_sizes[0] / 3;   // 500,000
  const int E = in_sizes[1] / 2;   // 8,000,000
  const int NB = (N + BSIZE - 1) >> BSHIFT;  // coarse buckets (489)
  const int NS = NB * NBLK;        // scan length (125,184)
  const int chunk = (E + NBLK - 1) / NBLK;

  // ---- workspace bump allocator (256B aligned); ~146 MB + optional 64 MB ----
  char* base = (char*)d_ws;
  size_t off = 0;
  auto alloc = [&](size_t bytes) -> void* {
    void* ptr = base + off;
    off = (off + bytes + 255) & ~size_t(255);
    return ptr;
  };
  unsigned* mat   = (unsigned*)alloc((size_t)NS * 4);
  unsigned* offs  = (unsigned*)alloc((size_t)(NS + 1) * 4);
  unsigned* btot  = (unsigned*)alloc(512 * 4);
  float*    diag  = (float*)alloc((size_t)N * 4);
  float*    minv  = (float*)alloc((size_t)N * 4);
  float*    phi   = (float*)alloc((size_t)N * 4);
  float*    rvec  = (float*)alloc((size_t)N * 4);
  float*    zvec  = (float*)alloc((size_t)N * 4);
  float*    pA    = (float*)alloc((size_t)N * 4);
  float*    pB    = (float*)alloc((size_t)N * 4);
  float*    ap    = (float*)alloc((size_t)N * 4);
  float*    rzrr  = (float*)alloc((size_t)(2 * (CG_ITERS + 1)) * KB * 4);
  float*    papp  = (float*)alloc((size_t)CG_ITERS * KB * 4);
  uint4*    A16   = (uint4*)alloc((size_t)E * 16);
  unsigned long long* A1hot = nullptr;
  if (off + (size_t)E * 8 + 256 <= ws_size)
    A1hot = (unsigned long long*)alloc((size_t)E * 8);
  (void)n_in; (void)out_size;

  auto rz_part = [&](int it) { return rzrr + (size_t)(2 * it) * KB; };
  auto rr_part = [&](int it) { return rzrr + (size_t)(2 * it + 1) * KB; };
  auto pap_part = [&](int it) { return papp + (size_t)it * KB; };

  const int nbScan = (NS + 1023) / 1024;          // 123 <= 512
  const int gridScanAdd = (NS + TPB - 1) / TPB;

  bucket_hist<<<NBLK, TPB_A, 0, stream>>>(ei, mat, E, NB, chunk);

  scan_blocks<<<nbScan, TPB, 0, stream>>>(mat, offs, btot, NS);
  scan_totals<<<1, 512, 0, stream>>>(btot, nbScan);
  scan_add<<<gridScanAdd, TPB, 0, stream>>>(offs, btot, NS, (unsigned)E);

  bucket_place<<<NBLK, TPB_A, 0, stream>>>(ei, u_hat, fn, fa, fd, offs,
                                           A16, E, NB, chunk);

  node_setup<<<KB, TPB_B, 0, stream>>>(A16, A1hot, offs, cv, diag,
                                       rvec, pA, phi, minv,
                                       rz_part(0), rr_part(0), N, NB);

  for (int it = 0; it < CG_ITERS; it++) {
    const float* pold;
    float* pnew;
    const float* pcur;
    int first = (it == 0) ? 1 : 0;
    if (it == 0) {
      pold = pA; pnew = pB; pcur = pA;          // pnew unused when first
    } else if (it & 1) {
      pold = pA; pnew = pB; pcur = pB;
    } else {
      pold = pB; pnew = pA; pcur = pA;
    }
    // beta_J = rz_J / rz_{J-1}, gated on rr_{J-1} (J = it)
    const float* rzJ   = rz_part(it);
    const float* rzJm1 = rz_part(it > 0 ? it - 1 : 0);
    const float* rrJm1 = rr_part(it > 0 ? it - 1 : 0);
    matvec<<<KB, TPB_B, 0, stream>>>(pold, pnew, zvec, diag, offs, A1hot, A16,
                                     ap, pap_part(it), rzJ, rzJm1, rrJm1,
                                     N, NB, first);
    cg_update<<<KB, TPB, 0, stream>>>(phi, rvec, pcur, ap, minv, zvec,
                                      pap_part(it), rz_part(it), rr_part(it),
                                      rz_part(it + 1), rr_part(it + 1), N);
  }

  finalize<<<NB, TPB_B, 0, stream>>>(u_hat, cv, phi, offs, A16,
                                     fn, out, N, NB);
}